// Round 1
// baseline (3343.993 us; speedup 1.0000x reference)
//
#include <hip/hip_runtime.h>

#define B_ 4
#define H_ 256
#define W_ 256
#define Z_ 64
#define NB_ (H_*W_*Z_)      /* 4194304 */
#define N_  (B_*NB_)        /* 16777216 */
#define ITER_ 8
#define EPS_ 1e-6f
#define SLOTS_ 64

#define GRID_  2048          /* exactly 8 blocks/CU * 256 CUs -> all co-resident */
#define TPB_   256
#define NTILE_ 8192          /* (W_/32) * H_ * B_ */
#define TILES_ (NTILE_/GRID_)/* 4 tiles per block */
static_assert(NTILE_ % GRID_ == 0, "tile split");

/* scal layout (floats) */
#define RHO_OFF   0
#define ETA_OFF   ((ITER_+1)*B_*SLOTS_)
#define LOSS_OFF  (ETA_OFF + ITER_*B_*SLOTS_)
#define MAXE_OFF  (LOSS_OFF + SLOTS_)
#define BAR_OFF   (MAXE_OFF + SLOTS_)   /* 64 u32 arrive counters (monotonic) */
#define GEN_OFF   (BAR_OFF + 64)        /* generation counter, own cache line */
#define SCAL_FLOATS (GEN_OFF + 32)

struct F8 { float4 a, b; };

__device__ __forceinline__ float wsum(float v){
  v += __shfl_xor(v,32); v += __shfl_xor(v,16); v += __shfl_xor(v,8);
  v += __shfl_xor(v,4);  v += __shfl_xor(v,2);  v += __shfl_xor(v,1);
  return v;
}
__device__ __forceinline__ float wmaxr(float v){
  v = fmaxf(v,__shfl_xor(v,32)); v = fmaxf(v,__shfl_xor(v,16));
  v = fmaxf(v,__shfl_xor(v,8));  v = fmaxf(v,__shfl_xor(v,4));
  v = fmaxf(v,__shfl_xor(v,2));  v = fmaxf(v,__shfl_xor(v,1));
  return v;
}
__device__ __forceinline__ float read_sum(const float* s){
  return wsum(s[threadIdx.x & 63]);
}
__device__ __forceinline__ void block_atomic_sum(float v, float* dst, float* lds){
  v = wsum(v);
  int wid = threadIdx.x >> 6, lane = threadIdx.x & 63;
  if (lane == 0) lds[wid] = v;
  __syncthreads();
  if (threadIdx.x == 0) atomicAdd(dst, lds[0]+lds[1]+lds[2]+lds[3]);
  __syncthreads();   /* lds reused next tile */
}

__device__ __forceinline__ float4 ld4(const float* p){ return *(const float4*)p; }

__device__ __forceinline__ void sub8(F8& s, const F8& n){
  s.a.x-=n.a.x; s.a.y-=n.a.y; s.a.z-=n.a.z; s.a.w-=n.a.w;
  s.b.x-=n.b.x; s.b.y-=n.b.y; s.b.z-=n.b.z; s.b.w-=n.b.w;
}

/* z-direction part of the stencil; zl/zr come from neighbor LANES via shuffle
   (they are the prev/next lane's already-loaded center values) */
__device__ __forceinline__ void zcore(const F8& c, int zc, F8& st){
  const int lane = threadIdx.x & 63;
  float zl = __shfl(c.b.w, (lane-1)&63);
  float zr = __shfl(c.a.x, (lane+1)&63);
  zl = (zc > 0) ? zl : 0.f;
  zr = (zc < 7) ? zr : 0.f;
  st.a.x = 6.f*c.a.x - zl    - c.a.y;
  st.a.y = 6.f*c.a.y - c.a.x - c.a.z;
  st.a.z = 6.f*c.a.z - c.a.y - c.a.w;
  st.a.w = 6.f*c.a.w - c.a.z - c.b.x;
  st.b.x = 6.f*c.b.x - c.a.w - c.b.y;
  st.b.y = 6.f*c.b.y - c.b.x - c.b.z;
  st.b.z = 6.f*c.b.z - c.b.y - c.b.w;
  st.b.w = 6.f*c.b.w - c.b.z - zr;
}

__device__ __forceinline__ void stencil1(const float* __restrict__ a, int base,
                                         int w, int h, int zc, F8& c, F8& st)
{
  c.a = ld4(a+base); c.b = ld4(a+base+4);
  zcore(c, zc, st);
  F8 t;
  if (w > 0)    { t.a = ld4(a+base-Z_);    t.b = ld4(a+base-Z_+4);    sub8(st,t); }
  if (w < W_-1) { t.a = ld4(a+base+Z_);    t.b = ld4(a+base+Z_+4);    sub8(st,t); }
  if (h > 0)    { t.a = ld4(a+base-W_*Z_); t.b = ld4(a+base-W_*Z_+4); sub8(st,t); }
  if (h < H_-1) { t.a = ld4(a+base+W_*Z_); t.b = ld4(a+base+W_*Z_+4); sub8(st,t); }
}

__device__ __forceinline__ F8 comb8(const float* r, const float* p, float beta, int idx){
  F8 o;
  float4 ra = ld4(r+idx), rb = ld4(r+idx+4);
  float4 pa = ld4(p+idx), pb = ld4(p+idx+4);
  o.a.x = ra.x + beta*pa.x; o.a.y = ra.y + beta*pa.y;
  o.a.z = ra.z + beta*pa.z; o.a.w = ra.w + beta*pa.w;
  o.b.x = rb.x + beta*pb.x; o.b.y = rb.y + beta*pb.y;
  o.b.z = rb.z + beta*pb.z; o.b.w = rb.w + beta*pb.w;
  return o;
}
__device__ __forceinline__ void stencil2(const float* __restrict__ r,
                                         const float* __restrict__ p, float beta,
                                         int base, int w, int h, int zc,
                                         F8& c, F8& st)
{
  c = comb8(r,p,beta,base);
  zcore(c, zc, st);
  if (w > 0)    sub8(st, comb8(r,p,beta,base-Z_));
  if (w < W_-1) sub8(st, comb8(r,p,beta,base+Z_));
  if (h > 0)    sub8(st, comb8(r,p,beta,base-W_*Z_));
  if (h < H_-1) sub8(st, comb8(r,p,beta,base+W_*Z_));
}

/* ---- device-wide barrier: distributed arrive + generation broadcast ---- */
__device__ __forceinline__ void gsync(unsigned* bars, unsigned* gen, unsigned epoch){
  __syncthreads();
  if (threadIdx.x == 0) {
    __threadfence();  /* release: write back this XCD's dirty L2 lines */
    __hip_atomic_fetch_add(&bars[blockIdx.x & 63], 1u,
                           __ATOMIC_RELAXED, __HIP_MEMORY_SCOPE_AGENT);
  }
  if (blockIdx.x == 0) {
    if (threadIdx.x < 64) {
      const unsigned tgt = epoch * (GRID_/64);
      while (__hip_atomic_load(&bars[threadIdx.x],
                               __ATOMIC_RELAXED, __HIP_MEMORY_SCOPE_AGENT) < tgt)
        __builtin_amdgcn_s_sleep(2);
    }
    __syncthreads();
    if (threadIdx.x == 0) {
      __threadfence();  /* acquire before release of others */
      __hip_atomic_fetch_add(gen, 1u, __ATOMIC_RELAXED, __HIP_MEMORY_SCOPE_AGENT);
    }
  } else {
    if (threadIdx.x == 0) {
      while (__hip_atomic_load(gen, __ATOMIC_RELAXED,
                               __HIP_MEMORY_SCOPE_AGENT) < epoch)
        __builtin_amdgcn_s_sleep(2);
      __threadfence();  /* acquire: invalidate stale L1/L2 */
    }
  }
  __syncthreads();
}

/* tile -> block map: each XCD (blockIdx&7) owns one 32-wide w-slab; each block
   gets TILES_ h-consecutive tiles of that slab (tile j+1's center row == tile
   j's h+1 halo -> L1 hit). T reproduces the original flat id. */
#define TILE_OF(j) ((((int)(blockIdx.x >> 3) * TILES_ + (j)) << 3) | (int)(blockIdx.x & 7))

#define TILE_SETUP(T) \
  const int tx = (T) & 7; \
  const int hh = ((T) >> 3) & 255; \
  const int bb = (T) >> 11; \
  const int w  = tx*32 + wl; \
  const int base = ((bb*H_ + hh)*W_ + w)*Z_ + zc*8; \
  const int slot = (T) & 63;

#define XI(k) ((((k) >> 3)*9) + ((k) & 7))   /* padded LDS index, stride 9 */

__global__ __launch_bounds__(TPB_, 8)
void k_cg(float* x, const float* __restrict__ bv, const float* __restrict__ ref,
          float* out, float* __restrict__ r, float* p0, float* p1,
          float* __restrict__ scal)
{
  __shared__ float xs[256*9];   /* 9216 B: padded x_new staging (fin phase) */
  __shared__ float lds[12];
  unsigned* bars = (unsigned*)(scal + BAR_OFF);
  unsigned* gen  = (unsigned*)(scal + GEN_OFF);

  const int zc = threadIdx.x & 7;
  const int wl = threadIdx.x >> 3;
  const int t  = threadIdx.x;
  unsigned ep = 0;

  /* ---- phase 0: r = b - A x ; rho0 ---- */
  #pragma unroll 1
  for (int j = 0; j < TILES_; ++j) {
    const int T = TILE_OF(j);
    TILE_SETUP(T)
    F8 c, st;
    stencil1(x, base, w, hh, zc, c, st);
    float4 b0 = ld4(bv+base), b1 = ld4(bv+base+4);
    F8 rv;
    rv.a = make_float4(b0.x-st.a.x, b0.y-st.a.y, b0.z-st.a.z, b0.w-st.a.w);
    rv.b = make_float4(b1.x-st.b.x, b1.y-st.b.y, b1.z-st.b.z, b1.w-st.b.w);
    *(float4*)(r+base)   = rv.a;
    *(float4*)(r+base+4) = rv.b;
    float rho = rv.a.x*rv.a.x + rv.a.y*rv.a.y + rv.a.z*rv.a.z + rv.a.w*rv.a.w
              + rv.b.x*rv.b.x + rv.b.y*rv.b.y + rv.b.z*rv.b.z + rv.b.w*rv.b.w;
    block_atomic_sum(rho, scal + RHO_OFF + (0*B_+bb)*SLOTS_ + slot, lds);
  }
  gsync(bars, gen, ++ep);

  float* pa = p1;   /* it even writes p1, odd writes p0 -> it=7 lands on p0 */
  float* pb = p0;

  for (int it = 0; it < ITER_; ++it) {
    /* ---- A phase: p_new (+eta = <p_new, A p_new>) ---- */
    if (it == 0) {
      #pragma unroll 1
      for (int j = 0; j < TILES_; ++j) {
        const int T = TILE_OF(j);
        TILE_SETUP(T)
        F8 c, st;
        stencil1(r, base, w, hh, zc, c, st);
        *(float4*)(pa+base)   = c.a;
        *(float4*)(pa+base+4) = c.b;
        float eta = c.a.x*st.a.x + c.a.y*st.a.y + c.a.z*st.a.z + c.a.w*st.a.w
                  + c.b.x*st.b.x + c.b.y*st.b.y + c.b.z*st.b.z + c.b.w*st.b.w;
        block_atomic_sum(eta, scal + ETA_OFF + (0*B_+bb)*SLOTS_ + slot, lds);
      }
    } else {
      #pragma unroll 1
      for (int j = 0; j < TILES_; ++j) {
        const int T = TILE_OF(j);
        TILE_SETUP(T)
        float num = read_sum(scal + RHO_OFF + (it*B_+bb)*SLOTS_);
        float den = read_sum(scal + RHO_OFF + ((it-1)*B_+bb)*SLOTS_);
        float beta = num / (den + EPS_);
        F8 c, st;
        stencil2(r, pb, beta, base, w, hh, zc, c, st);
        *(float4*)(pa+base)   = c.a;
        *(float4*)(pa+base+4) = c.b;
        float eta = c.a.x*st.a.x + c.a.y*st.a.y + c.a.z*st.a.z + c.a.w*st.a.w
                  + c.b.x*st.b.x + c.b.y*st.b.y + c.b.z*st.b.z + c.b.w*st.b.w;
        block_atomic_sum(eta, scal + ETA_OFF + (it*B_+bb)*SLOTS_ + slot, lds);
      }
    }
    gsync(bars, gen, ++ep);

    /* ---- B phase: x += alpha p ; r -= alpha A p ; rho_next ---- */
    if (it < ITER_-1) {
      #pragma unroll 1
      for (int j = 0; j < TILES_; ++j) {
        const int T = TILE_OF(j);
        TILE_SETUP(T)
        float num = read_sum(scal + RHO_OFF + (it*B_+bb)*SLOTS_);
        float den = read_sum(scal + ETA_OFF + (it*B_+bb)*SLOTS_);
        float alpha = num / (den + EPS_);
        F8 c, st;
        stencil1(pa, base, w, hh, zc, c, st);
        float4 x0 = ld4(x+base), x1 = ld4(x+base+4);
        x0.x += alpha*c.a.x; x0.y += alpha*c.a.y; x0.z += alpha*c.a.z; x0.w += alpha*c.a.w;
        x1.x += alpha*c.b.x; x1.y += alpha*c.b.y; x1.z += alpha*c.b.z; x1.w += alpha*c.b.w;
        *(float4*)(x+base)   = x0;
        *(float4*)(x+base+4) = x1;
        float4 r0 = ld4(r+base), r1 = ld4(r+base+4);
        r0.x -= alpha*st.a.x; r0.y -= alpha*st.a.y; r0.z -= alpha*st.a.z; r0.w -= alpha*st.a.w;
        r1.x -= alpha*st.b.x; r1.y -= alpha*st.b.y; r1.z -= alpha*st.b.z; r1.w -= alpha*st.b.w;
        *(float4*)(r+base)   = r0;
        *(float4*)(r+base+4) = r1;
        float rho = r0.x*r0.x + r0.y*r0.y + r0.z*r0.z + r0.w*r0.w
                  + r1.x*r1.x + r1.y*r1.y + r1.z*r1.z + r1.w*r1.w;
        block_atomic_sum(rho, scal + RHO_OFF + ((it+1)*B_+bb)*SLOTS_ + slot, lds);
      }
    } else {
      /* ---- final B phase fused with epilogue ---- */
      #pragma unroll 1
      for (int j = 0; j < TILES_; ++j) {
        const int T = TILE_OF(j);
        TILE_SETUP(T)
        float num = read_sum(scal + RHO_OFF + (it*B_+bb)*SLOTS_);
        float den = read_sum(scal + ETA_OFF + (it*B_+bb)*SLOTS_);
        float alpha = num / (den + EPS_);
        F8 c, st;
        stencil1(pa, base, w, hh, zc, c, st);
        float4 x0 = ld4(x+base), x1 = ld4(x+base+4);
        x0.x += alpha*c.a.x; x0.y += alpha*c.a.y; x0.z += alpha*c.a.z; x0.w += alpha*c.a.w;
        x1.x += alpha*c.b.x; x1.y += alpha*c.b.y; x1.z += alpha*c.b.z; x1.w += alpha*c.b.w;
        float4 r0 = ld4(r+base), r1 = ld4(r+base+4);
        r0.x -= alpha*st.a.x; r0.y -= alpha*st.a.y; r0.z -= alpha*st.a.z; r0.w -= alpha*st.a.w;
        r1.x -= alpha*st.b.x; r1.y -= alpha*st.b.y; r1.z -= alpha*st.b.z; r1.w -= alpha*st.b.w;
        float rho = r0.x*r0.x + r0.y*r0.y + r0.z*r0.z + r0.w*r0.w
                  + r1.x*r1.x + r1.y*r1.y + r1.z*r1.z + r1.w*r1.w;

        /* stage x_new to LDS (padded: group stride 9 -> no bank conflicts) */
        xs[t*9+0] = x0.x; xs[t*9+1] = x0.y; xs[t*9+2] = x0.z; xs[t*9+3] = x0.w;
        xs[t*9+4] = x1.x; xs[t*9+5] = x1.y; xs[t*9+6] = x1.z; xs[t*9+7] = x1.w;

        float4 f0 = ld4(ref+base), f1 = ld4(ref+base+4);
        float d0 = x0.x-f0.x, d1 = x0.y-f0.y, d2 = x0.z-f0.z, d3 = x0.w-f0.w;
        float d4 = x1.x-f1.x, d5 = x1.y-f1.y, d6 = x1.z-f1.z, d7 = x1.w-f1.w;
        float loss = d0*d0+d1*d1+d2*d2+d3*d3+d4*d4+d5*d5+d6*d6+d7*d7;
        float me = fmaxf(fmaxf(fmaxf(fabsf(d0),fabsf(d1)),fmaxf(fabsf(d2),fabsf(d3))),
                         fmaxf(fmaxf(fabsf(d4),fabsf(d5)),fmaxf(fabsf(d6),fabsf(d7))));

        float rs = wsum(rho), ls = wsum(loss), ms = wmaxr(me);
        int wid = t >> 6, lane = t & 63;
        if (lane == 0) { lds[wid] = rs; lds[4+wid] = ls; lds[8+wid] = ms; }
        __syncthreads();
        if (t == 0) {
          atomicAdd(scal + RHO_OFF + ((it+1)*B_+bb)*SLOTS_ + slot, lds[0]+lds[1]+lds[2]+lds[3]);
          atomicAdd(scal + LOSS_OFF + slot, lds[4]+lds[5]+lds[6]+lds[7]);
          float bm = fmaxf(fmaxf(lds[8],lds[9]), fmaxf(lds[10],lds[11]));
          atomicMax((unsigned int*)(scal + MAXE_OFF) + slot, __float_as_uint(bm));
        }

        /* aligned shifted stores: out span [1+S, 2048+S] */
        const int S = T * 2048;
        #pragma unroll
        for (int c2 = 0; c2 < 2; ++c2) {
          int q = t + 256*c2;
          if (q < 511) {
            int k = 4*q + 3;
            float4 v = make_float4(xs[XI(k)], xs[XI(k+1)], xs[XI(k+2)], xs[XI(k+3)]);
            *(float4*)(out + S + 4 + 4*q) = v;
          } else if (q == 511) {
            out[S+1] = xs[XI(0)]; out[S+2] = xs[XI(1)]; out[S+3] = xs[XI(2)];
            out[S+2048] = xs[XI(2047)];
          }
        }
        __syncthreads();   /* xs/lds reused next tile */
      }
    }
    gsync(bars, gen, ++ep);
    float* tmp = pa; pa = pb; pb = tmp;
  }

  /* ---- final scalars (one wave of block 0) ---- */
  if (blockIdx.x == 0 && t < 64) {
    int lane = t;
    float loss = wsum(scal[LOSS_OFF + lane]);
    float me   = wmaxr(__uint_as_float(((const unsigned int*)scal)[MAXE_OFF + lane]));
    float rho_sum = 0.f;
    for (int bb = 0; bb < B_; ++bb)
      rho_sum += wsum(scal[RHO_OFF + (ITER_*B_+bb)*SLOTS_ + lane]);
    if (lane == 0) {
      out[0]    = loss / (float)N_;
      out[1+N_] = me;
      out[2+N_] = rho_sum / (float)B_;
    }
  }
}

extern "C" void kernel_launch(void* const* d_in, const int* in_sizes, int n_in,
                              void* d_out, int out_size, void* d_ws, size_t ws_size,
                              hipStream_t stream) {
  float* x         = (float*)d_in[0];
  const float* bv  = (const float*)d_in[1];
  const float* ref = (const float*)d_in[2];
  float* out       = (float*)d_out;

  float* r  = (float*)d_ws;
  float* p0 = r + N_;
  float* p1;
  float* scal;
  size_t need3 = ((size_t)3*N_ + SCAL_FLOATS) * sizeof(float);
  if (ws_size >= need3) {
    p1   = p0 + N_;
    scal = p1 + N_;
  } else {
    /* fallback: d_out is scratch until the final phase; parity guarantees
       the final iteration reads p0 (real ws), never d_out. */
    p1   = out;
    scal = p0 + N_;
  }

  (void)hipMemsetAsync(scal, 0, SCAL_FLOATS*sizeof(float), stream);

  k_cg<<<dim3(GRID_), dim3(TPB_), 0, stream>>>(x, bv, ref, out, r, p0, p1, scal);
}

// Round 3
// 1117.546 us; speedup vs baseline: 2.9923x; 2.9923x over previous
//
#include <hip/hip_runtime.h>

#define B_ 4
#define H_ 256
#define W_ 256
#define Z_ 64
#define NB_ (H_*W_*Z_)      /* 4194304 */
#define N_  (B_*NB_)        /* 16777216 */
#define ITER_ 8
#define EPS_ 1e-6f
#define SLOTS_ 64
#define NTILE_ 8192

/* scal layout (floats) */
#define RHO_OFF   0
#define ETA_OFF   ((ITER_+1)*B_*SLOTS_)
#define LOSS_OFF  (ETA_OFF + ITER_*B_*SLOTS_)
#define MAXE_OFF  (LOSS_OFF + SLOTS_)
#define TICK_OFF  (MAXE_OFF + SLOTS_)
#define SCAL_FLOATS (TICK_OFF + 32)

struct F8 { float4 a, b; };

typedef float vf4 __attribute__((ext_vector_type(4)));

__device__ __forceinline__ float4 ldnt4(const float* p){
  vf4 v = __builtin_nontemporal_load((const vf4*)p);
  return make_float4(v.x, v.y, v.z, v.w);
}
__device__ __forceinline__ void stnt4(float* p, float4 v){
  vf4 t; t.x = v.x; t.y = v.y; t.z = v.z; t.w = v.w;
  __builtin_nontemporal_store(t, (vf4*)p);
}

__device__ __forceinline__ float wsum(float v){
  v += __shfl_xor(v,32); v += __shfl_xor(v,16); v += __shfl_xor(v,8);
  v += __shfl_xor(v,4);  v += __shfl_xor(v,2);  v += __shfl_xor(v,1);
  return v;
}
__device__ __forceinline__ float wmaxr(float v){
  v = fmaxf(v,__shfl_xor(v,32)); v = fmaxf(v,__shfl_xor(v,16));
  v = fmaxf(v,__shfl_xor(v,8));  v = fmaxf(v,__shfl_xor(v,4));
  v = fmaxf(v,__shfl_xor(v,2));  v = fmaxf(v,__shfl_xor(v,1));
  return v;
}
__device__ __forceinline__ float read_sum(const float* s){
  return wsum(s[threadIdx.x & 63]);
}
__device__ __forceinline__ void block_atomic_sum(float v, float* dst, float* lds){
  v = wsum(v);
  int wid = threadIdx.x >> 6, lane = threadIdx.x & 63;
  if (lane == 0) lds[wid] = v;
  __syncthreads();
  if (threadIdx.x == 0) atomicAdd(dst, lds[0]+lds[1]+lds[2]+lds[3]);
}

__device__ __forceinline__ float4 ld4(const float* p){ return *(const float4*)p; }

__device__ __forceinline__ void sub8(F8& s, const F8& n){
  s.a.x-=n.a.x; s.a.y-=n.a.y; s.a.z-=n.a.z; s.a.w-=n.a.w;
  s.b.x-=n.b.x; s.b.y-=n.b.y; s.b.z-=n.b.z; s.b.w-=n.b.w;
}

/* z-part of stencil: zl/zr via wave shuffle (neighbor lane's center values).
   lane L has zc = L&7; zc>0 -> zl = lane L-1's c.b.w; zc<7 -> zr = lane L+1's c.a.x */
__device__ __forceinline__ void zcore(const F8& c, int zc, F8& st){
  float zl = __shfl_up(c.b.w, 1);
  float zr = __shfl_down(c.a.x, 1);
  zl = (zc > 0) ? zl : 0.f;
  zr = (zc < 7) ? zr : 0.f;
  st.a.x = 6.f*c.a.x - zl    - c.a.y;
  st.a.y = 6.f*c.a.y - c.a.x - c.a.z;
  st.a.z = 6.f*c.a.z - c.a.y - c.a.w;
  st.a.w = 6.f*c.a.w - c.a.z - c.b.x;
  st.b.x = 6.f*c.b.x - c.a.w - c.b.y;
  st.b.y = 6.f*c.b.y - c.b.x - c.b.z;
  st.b.z = 6.f*c.b.z - c.b.y - c.b.w;
  st.b.w = 6.f*c.b.w - c.b.z - zr;
}

__device__ __forceinline__ void stencil1(const float* __restrict__ a, int base,
                                         int w, int h, int zc, F8& c, F8& st)
{
  c.a = ld4(a+base); c.b = ld4(a+base+4);
  zcore(c, zc, st);
  F8 t;
  if (w > 0)    { t.a = ld4(a+base-Z_);    t.b = ld4(a+base-Z_+4);    sub8(st,t); }
  if (w < W_-1) { t.a = ld4(a+base+Z_);    t.b = ld4(a+base+Z_+4);    sub8(st,t); }
  if (h > 0)    { t.a = ld4(a+base-W_*Z_); t.b = ld4(a+base-W_*Z_+4); sub8(st,t); }
  if (h < H_-1) { t.a = ld4(a+base+W_*Z_); t.b = ld4(a+base+W_*Z_+4); sub8(st,t); }
}

__device__ __forceinline__ F8 comb8(const float* r, const float* p, float beta, int idx){
  F8 o;
  float4 ra = ld4(r+idx), rb = ld4(r+idx+4);
  float4 pa = ld4(p+idx), pb = ld4(p+idx+4);
  o.a.x = ra.x + beta*pa.x; o.a.y = ra.y + beta*pa.y;
  o.a.z = ra.z + beta*pa.z; o.a.w = ra.w + beta*pa.w;
  o.b.x = rb.x + beta*pb.x; o.b.y = rb.y + beta*pb.y;
  o.b.z = rb.z + beta*pb.z; o.b.w = rb.w + beta*pb.w;
  return o;
}
__device__ __forceinline__ void stencil2(const float* __restrict__ r,
                                         const float* __restrict__ p, float beta,
                                         int base, int w, int h, int zc,
                                         F8& c, F8& st)
{
  c = comb8(r,p,beta,base);
  zcore(c, zc, st);
  if (w > 0)    sub8(st, comb8(r,p,beta,base-Z_));
  if (w < W_-1) sub8(st, comb8(r,p,beta,base+Z_));
  if (h > 0)    sub8(st, comb8(r,p,beta,base-W_*Z_));
  if (h < H_-1) sub8(st, comb8(r,p,beta,base+W_*Z_));
}

__device__ __forceinline__ float dot8(const F8& a, const F8& b){
  return a.a.x*b.a.x + a.a.y*b.a.y + a.a.z*b.a.z + a.a.w*b.a.w
       + a.b.x*b.b.x + a.b.y*b.b.y + a.b.z*b.b.z + a.b.w*b.b.w;
}

#define IDX_SETUP \
  const int zc = threadIdx.x & 7; \
  const int wl = threadIdx.x >> 3; \
  const int w  = blockIdx.x*32 + wl; \
  const int h  = blockIdx.y; \
  const int bb = blockIdx.z; \
  const int base = ((bb*H_ + h)*W_ + w)*Z_ + zc*8; \
  const int flat = (blockIdx.z*gridDim.y + blockIdx.y)*gridDim.x + blockIdx.x; \
  const int slot = flat & (SLOTS_-1);

#define XI(k) ((((k) >> 3)*9) + ((k) & 7))   /* padded LDS index, stride 9 */

/* r = b - A x ; rho0 = <r,r> per batch */
__global__ __launch_bounds__(256) void k_init(const float* __restrict__ x,
                                              const float* __restrict__ b,
                                              float* __restrict__ r,
                                              float* scal)
{
  __shared__ float lds[4];
  IDX_SETUP
  F8 c, st;
  stencil1(x, base, w, h, zc, c, st);
  float4 b0 = ldnt4(b+base);
  float4 b1 = ldnt4(b+base+4);
  F8 rv;
  rv.a = make_float4(b0.x-st.a.x, b0.y-st.a.y, b0.z-st.a.z, b0.w-st.a.w);
  rv.b = make_float4(b1.x-st.b.x, b1.y-st.b.y, b1.z-st.b.z, b1.w-st.b.w);
  *(float4*)(r+base)   = rv.a;
  *(float4*)(r+base+4) = rv.b;
  block_atomic_sum(dot8(rv,rv), scal + RHO_OFF + (0*B_+bb)*SLOTS_ + slot, lds);
}

/* it==0: eta0 = <r, A r>; optional p0 = r copy (fallback path only) */
__global__ __launch_bounds__(256) void k_a0(const float* __restrict__ r,
                                            float* __restrict__ pnew,
                                            float* scal)
{
  __shared__ float lds[4];
  IDX_SETUP
  F8 c, st;
  stencil1(r, base, w, h, zc, c, st);
  if (pnew) { *(float4*)(pnew+base) = c.a; *(float4*)(pnew+base+4) = c.b; }
  block_atomic_sum(dot8(c,st), scal + ETA_OFF + (0*B_+bb)*SLOTS_ + slot, lds);
}

/* it>=1: p_new = r + beta*p_old ; eta = <p_new, A p_new> per batch */
__global__ __launch_bounds__(256) void k_a(const float* __restrict__ r,
                                           const float* __restrict__ pold,
                                           float* __restrict__ pnew,
                                           float* scal, int it)
{
  __shared__ float lds[4];
  IDX_SETUP
  float num = read_sum(scal + RHO_OFF + (it*B_+bb)*SLOTS_);
  float den = read_sum(scal + RHO_OFF + ((it-1)*B_+bb)*SLOTS_);
  float beta = num / (den + EPS_);
  F8 c, st;
  stencil2(r, pold, beta, base, w, h, zc, c, st);
  *(float4*)(pnew+base)   = c.a;
  *(float4*)(pnew+base+4) = c.b;
  block_atomic_sum(dot8(c,st), scal + ETA_OFF + (it*B_+bb)*SLOTS_ + slot, lds);
}

/* it<7: alpha; x += alpha p; r_out = r_in - alpha*A p; rho_next = <r,r>.
   r_in may alias p (it==0, p0==r0) and r_out may alias r_in (in-place). */
__global__ __launch_bounds__(256) void k_b(float* __restrict__ x,
                                           const float* r_in,
                                           float* r_out,
                                           const float* p,
                                           float* scal, int it)
{
  __shared__ float lds[4];
  IDX_SETUP
  float num = read_sum(scal + RHO_OFF + (it*B_+bb)*SLOTS_);
  float den = read_sum(scal + ETA_OFF + (it*B_+bb)*SLOTS_);
  float alpha = num / (den + EPS_);
  F8 c, st;
  stencil1(p, base, w, h, zc, c, st);
  float4 x0 = ld4(x+base), x1 = ld4(x+base+4);
  x0.x += alpha*c.a.x; x0.y += alpha*c.a.y; x0.z += alpha*c.a.z; x0.w += alpha*c.a.w;
  x1.x += alpha*c.b.x; x1.y += alpha*c.b.y; x1.z += alpha*c.b.z; x1.w += alpha*c.b.w;
  *(float4*)(x+base)   = x0;
  *(float4*)(x+base+4) = x1;
  float4 r0 = ld4(r_in+base), r1 = ld4(r_in+base+4);
  r0.x -= alpha*st.a.x; r0.y -= alpha*st.a.y; r0.z -= alpha*st.a.z; r0.w -= alpha*st.a.w;
  r1.x -= alpha*st.b.x; r1.y -= alpha*st.b.y; r1.z -= alpha*st.b.z; r1.w -= alpha*st.b.w;
  *(float4*)(r_out+base)   = r0;
  *(float4*)(r_out+base+4) = r1;
  float rho = r0.x*r0.x + r0.y*r0.y + r0.z*r0.z + r0.w*r0.w
            + r1.x*r1.x + r1.y*r1.y + r1.z*r1.z + r1.w*r1.w;
  block_atomic_sum(rho, scal + RHO_OFF + ((it+1)*B_+bb)*SLOTS_ + slot, lds);
}

/* it==7 fused with epilogue + final scalar fold (last-block ticket). */
__global__ __launch_bounds__(256) void k_b_fin(const float* __restrict__ x,
                                               const float* __restrict__ r,
                                               const float* __restrict__ p,
                                               const float* __restrict__ ref,
                                               float* __restrict__ out,
                                               float* scal, int it)
{
  __shared__ float xs[256*9];   /* padded stride-9 staging: no bank conflicts */
  __shared__ float lds[12];
  __shared__ unsigned is_last;
  IDX_SETUP
  const int t = threadIdx.x;
  float num = read_sum(scal + RHO_OFF + (it*B_+bb)*SLOTS_);
  float den = read_sum(scal + ETA_OFF + (it*B_+bb)*SLOTS_);
  float alpha = num / (den + EPS_);
  F8 c, st;
  stencil1(p, base, w, h, zc, c, st);
  float4 x0 = ld4(x+base), x1 = ld4(x+base+4);
  x0.x += alpha*c.a.x; x0.y += alpha*c.a.y; x0.z += alpha*c.a.z; x0.w += alpha*c.a.w;
  x1.x += alpha*c.b.x; x1.y += alpha*c.b.y; x1.z += alpha*c.b.z; x1.w += alpha*c.b.w;
  float4 r0 = ld4(r+base), r1 = ld4(r+base+4);
  r0.x -= alpha*st.a.x; r0.y -= alpha*st.a.y; r0.z -= alpha*st.a.z; r0.w -= alpha*st.a.w;
  r1.x -= alpha*st.b.x; r1.y -= alpha*st.b.y; r1.z -= alpha*st.b.z; r1.w -= alpha*st.b.w;
  float rho = r0.x*r0.x + r0.y*r0.y + r0.z*r0.z + r0.w*r0.w
            + r1.x*r1.x + r1.y*r1.y + r1.z*r1.z + r1.w*r1.w;

  xs[t*9+0] = x0.x; xs[t*9+1] = x0.y; xs[t*9+2] = x0.z; xs[t*9+3] = x0.w;
  xs[t*9+4] = x1.x; xs[t*9+5] = x1.y; xs[t*9+6] = x1.z; xs[t*9+7] = x1.w;

  float4 f0 = ldnt4(ref+base);
  float4 f1 = ldnt4(ref+base+4);
  float d0 = x0.x-f0.x, d1 = x0.y-f0.y, d2 = x0.z-f0.z, d3 = x0.w-f0.w;
  float d4 = x1.x-f1.x, d5 = x1.y-f1.y, d6 = x1.z-f1.z, d7 = x1.w-f1.w;
  float loss = d0*d0+d1*d1+d2*d2+d3*d3+d4*d4+d5*d5+d6*d6+d7*d7;
  float me = fmaxf(fmaxf(fmaxf(fabsf(d0),fabsf(d1)),fmaxf(fabsf(d2),fabsf(d3))),
                   fmaxf(fmaxf(fabsf(d4),fabsf(d5)),fmaxf(fabsf(d6),fabsf(d7))));

  float rs = wsum(rho), ls = wsum(loss), ms = wmaxr(me);
  int wid = t >> 6, lane = t & 63;
  if (lane == 0) { lds[wid] = rs; lds[4+wid] = ls; lds[8+wid] = ms; }
  __syncthreads();
  if (t == 0) {
    atomicAdd(scal + RHO_OFF + ((it+1)*B_+bb)*SLOTS_ + slot, lds[0]+lds[1]+lds[2]+lds[3]);
    atomicAdd(scal + LOSS_OFF + slot, lds[4]+lds[5]+lds[6]+lds[7]);
    float bm = fmaxf(fmaxf(lds[8],lds[9]), fmaxf(lds[10],lds[11]));
    atomicMax((unsigned int*)(scal + MAXE_OFF) + slot, __float_as_uint(bm));
    /* order the above device-scope atomics before the ticket */
    asm volatile("s_waitcnt vmcnt(0)" ::: "memory");
    unsigned old = __hip_atomic_fetch_add((unsigned*)(scal + TICK_OFF), 1u,
                                          __ATOMIC_RELAXED, __HIP_MEMORY_SCOPE_AGENT);
    is_last = (old == NTILE_-1) ? 1u : 0u;
  }

  /* aligned shifted stores: out span [1+S, 2048+S] */
  const int S = flat * 2048;
  #pragma unroll
  for (int c2 = 0; c2 < 2; ++c2) {
    int q = t + 256*c2;
    if (q < 511) {
      int k = 4*q + 3;
      float4 v = make_float4(xs[XI(k)], xs[XI(k+1)], xs[XI(k+2)], xs[XI(k+3)]);
      stnt4(out + S + 4 + 4*q, v);
    } else if (q == 511) {
      out[S+1] = xs[XI(0)]; out[S+2] = xs[XI(1)]; out[S+3] = xs[XI(2)];
      out[S+2048] = xs[XI(2047)];
    }
  }

  __syncthreads();
  /* last block folds the final scalars (reads via agent-scope atomic loads) */
  if (is_last && t < 64) {
    float lossv = wsum(__hip_atomic_load(scal + LOSS_OFF + t,
                                         __ATOMIC_RELAXED, __HIP_MEMORY_SCOPE_AGENT));
    unsigned mu = __hip_atomic_load((unsigned*)scal + MAXE_OFF + t,
                                    __ATOMIC_RELAXED, __HIP_MEMORY_SCOPE_AGENT);
    float mev = wmaxr(__uint_as_float(mu));
    float rho_sum = 0.f;
    for (int b2 = 0; b2 < B_; ++b2)
      rho_sum += wsum(__hip_atomic_load(scal + RHO_OFF + (ITER_*B_+b2)*SLOTS_ + t,
                                        __ATOMIC_RELAXED, __HIP_MEMORY_SCOPE_AGENT));
    if (t == 0) {
      out[0]    = lossv / (float)N_;
      out[1+N_] = mev;
      out[2+N_] = rho_sum / (float)B_;
    }
  }
}

extern "C" void kernel_launch(void* const* d_in, const int* in_sizes, int n_in,
                              void* d_out, int out_size, void* d_ws, size_t ws_size,
                              hipStream_t stream) {
  float* x         = (float*)d_in[0];
  const float* bv  = (const float*)d_in[1];
  const float* ref = (const float*)d_in[2];
  float* out       = (float*)d_out;
  float* ws        = (float*)d_ws;

  dim3 grid(W_/32, H_, B_), blk(256);
  bool fast = ws_size >= ((size_t)3*N_ + SCAL_FLOATS) * sizeof(float);

  if (fast) {
    /* R0 = r0 (== p0), R1 = live r, P0/P1 = p ping-pong (P1 = out scratch) */
    float* R0 = ws;
    float* R1 = ws + N_;
    float* P0 = ws + 2*(size_t)N_;
    float* P1 = out;
    float* scal = ws + 3*(size_t)N_;
    (void)hipMemsetAsync(scal, 0, SCAL_FLOATS*sizeof(float), stream);

    k_init<<<grid, blk, 0, stream>>>(x, bv, R0, scal);
    k_a0  <<<grid, blk, 0, stream>>>(R0, nullptr, scal);          /* p0 == r0 */
    k_b   <<<grid, blk, 0, stream>>>(x, R0, R1, R0, scal, 0);     /* r1 -> R1 */
    float* pa = P0; float* pb = R0;
    for (int it = 1; it < ITER_; ++it) {
      k_a<<<grid, blk, 0, stream>>>(R1, pb, pa, scal, it);
      if (it < ITER_-1)
        k_b<<<grid, blk, 0, stream>>>(x, R1, R1, pa, scal, it);   /* in-place r */
      else
        k_b_fin<<<grid, blk, 0, stream>>>(x, R1, pa, ref, out, scal, it);
      pb = pa; pa = (pa == P0) ? P1 : P0;
    }
    /* parity: it=1..7 -> pa = P0,P1,P0,P1,P0,P1,P0 ; fin reads P0 (ws, not out) */
  } else {
    /* fallback: r in-place in ws0; p ping-pong ws1/out; it0 copies p0 to out */
    float* r    = ws;
    float* p0w  = ws + N_;
    float* scal = ws + 2*(size_t)N_;
    (void)hipMemsetAsync(scal, 0, SCAL_FLOATS*sizeof(float), stream);

    k_init<<<grid, blk, 0, stream>>>(x, bv, r, scal);
    k_a0  <<<grid, blk, 0, stream>>>(r, out, scal);               /* p0 -> out */
    k_b   <<<grid, blk, 0, stream>>>(x, r, r, out, scal, 0);
    float* pa = p0w; float* pb = out;
    for (int it = 1; it < ITER_; ++it) {
      k_a<<<grid, blk, 0, stream>>>(r, pb, pa, scal, it);
      if (it < ITER_-1)
        k_b<<<grid, blk, 0, stream>>>(x, r, r, pa, scal, it);
      else
        k_b_fin<<<grid, blk, 0, stream>>>(x, r, pa, ref, out, scal, it);
      pb = pa; pa = (pa == p0w) ? out : p0w;
    }
    /* parity: it=1..7 -> pa = ws1,out,ws1,out,ws1,out,ws1 ; fin reads ws1 */
  }
}